// Round 1
// baseline (77.011 us; speedup 1.0000x reference)
//
#include <hip/hip_runtime.h>
#include <hip/hip_bf16.h>
#include <stdint.h>

#define L_SEQ 2048
#define D_MODEL 1024
#define NH 16
#define DH 64
#define NEG_INF -1e9f
#define BM 128
#define BN 128
#define BK 32

typedef short bf16x8 __attribute__((ext_vector_type(8)));
typedef float f32x4 __attribute__((ext_vector_type(4)));
typedef unsigned short ushort_t;
typedef const __attribute__((address_space(1))) void* gas_t;
typedef __attribute__((address_space(3))) void* las_t;

#define MFMA16(a, b, c) __builtin_amdgcn_mfma_f32_16x16x32_bf16((a), (b), (c), 0, 0, 0)

__device__ __forceinline__ ushort_t f2b(float f) {
  union { float f; unsigned u; } v; v.f = f;
  unsigned r = v.u + 0x7fffu + ((v.u >> 16) & 1u);
  return (ushort_t)(r >> 16);
}

// ---------------- f32 -> bf16 conversion of x + 4 weights ----------------
__global__ __launch_bounds__(256) void cvt_kernel(
    const float* __restrict__ x, const float* __restrict__ wq,
    const float* __restrict__ wk, const float* __restrict__ wv,
    const float* __restrict__ wo, ushort_t* __restrict__ out) {
  long e = ((long)blockIdx.x * 256 + threadIdx.x) * 4;
  const float* src; long off;
  if (e < 2097152L)      { src = x;  off = e; }
  else if (e < 3145728L) { src = wq; off = e - 2097152L; }
  else if (e < 4194304L) { src = wk; off = e - 3145728L; }
  else if (e < 5242880L) { src = wv; off = e - 4194304L; }
  else                   { src = wo; off = e - 5242880L; }
  float4 v = *(const float4*)(src + off);
  ushort4 o;
  o.x = f2b(v.x); o.y = f2b(v.y); o.z = f2b(v.z); o.w = f2b(v.w);
  *(ushort4*)(out + e) = o;
}

// ---------------- bf16 NT GEMM (m97 structure): Y = A @ W^T + bias ----------------
// A: [2048][1024] bf16 row-major, W: [1024][1024] bf16 row-major (N x K)
// mode 0: out bf16 head-major [NH][L][DH], scale 0.125 for z==0 (Q)
// mode 1: out f32 row-major [2048][1024]
__global__ __launch_bounds__(256) void gemm_bt(
    const ushort_t* __restrict__ A, const ushort_t* __restrict__ Wbase,
    const float* __restrict__ b0, const float* __restrict__ b1,
    const float* __restrict__ b2, void* __restrict__ outbase, int mode) {
  const int z = blockIdx.z;
  const ushort_t* W = Wbase + (long)z * (D_MODEL * D_MODEL);
  const float* bias = (z == 0) ? b0 : ((z == 1) ? b1 : b2);
  const float scale = (mode == 0 && z == 0) ? 0.125f : 1.0f;

  __shared__ ushort_t As[BM * BK];
  __shared__ ushort_t Bs[BN * BK];
  const int tid = threadIdx.x;
  const int lane = tid & 63;
  const int wid = tid >> 6;
  const int wm = wid >> 1, wn = wid & 1;
  const int m0 = blockIdx.x * BM, n0 = blockIdx.y * BN;
  const int K = D_MODEL;
  const int l15 = lane & 15, lg8 = (lane >> 4) * 8;

  f32x4 acc[4][4] = {};

  for (int kt = 0; kt < K; kt += BK) {
#pragma unroll
    for (int i = 0; i < 2; ++i) {
      int off = tid * 16 + i * 4096;      // byte offset into 8KB tile
      int row = off >> 6;                 // 64B per row (32 bf16)
      int cole = (off & 63) >> 1;         // element within row
      __builtin_amdgcn_global_load_lds(
          (gas_t)(const void*)(A + (long)(m0 + row) * K + kt + cole),
          (las_t)(void*)((char*)As + off), 16, 0, 0);
      __builtin_amdgcn_global_load_lds(
          (gas_t)(const void*)(W + (long)(n0 + row) * K + kt + cole),
          (las_t)(void*)((char*)Bs + off), 16, 0, 0);
    }
    __syncthreads();
    bf16x8 af[4], bf[4];
#pragma unroll
    for (int t = 0; t < 4; ++t) {
      af[t] = *(const bf16x8*)(As + (wm * 64 + t * 16 + l15) * BK + lg8);
      bf[t] = *(const bf16x8*)(Bs + (wn * 64 + t * 16 + l15) * BK + lg8);
    }
#pragma unroll
    for (int mt = 0; mt < 4; ++mt)
#pragma unroll
      for (int nt = 0; nt < 4; ++nt)
        acc[mt][nt] = MFMA16(af[mt], bf[nt], acc[mt][nt]);
    __syncthreads();
  }

  const int lg4 = (lane >> 4) * 4;
  if (mode == 0) {
    ushort_t* o = (ushort_t*)outbase + (long)z * ((long)NH * L_SEQ * DH);
#pragma unroll
    for (int mt = 0; mt < 4; ++mt)
#pragma unroll
      for (int nt = 0; nt < 4; ++nt)
#pragma unroll
        for (int r = 0; r < 4; ++r) {
          int row = m0 + wm * 64 + mt * 16 + lg4 + r;
          int col = n0 + wn * 64 + nt * 16 + l15;
          float v = (acc[mt][nt][r] + bias[col]) * scale;
          o[((long)(col >> 6) * L_SEQ + row) * DH + (col & 63)] = f2b(v);
        }
  } else {
    float* o = (float*)outbase;
#pragma unroll
    for (int mt = 0; mt < 4; ++mt)
#pragma unroll
      for (int nt = 0; nt < 4; ++nt)
#pragma unroll
        for (int r = 0; r < 4; ++r) {
          int row = m0 + wm * 64 + mt * 16 + lg4 + r;
          int col = n0 + wn * 64 + nt * 16 + l15;
          o[(long)row * D_MODEL + col] = acc[mt][nt][r] + bias[col];
        }
  }
}

// ---------------- fused local+global sparse attention ----------------
// Grid: (32 q-blocks, 16 heads), 256 threads (4 waves x 16 queries).
// Swapped QK^T (mfma(K,Q)): S^T tiles have col=lane&15=query, rows=keys.
__global__ __launch_bounds__(256) void attn_kernel(
    const ushort_t* __restrict__ QKV, const int* __restrict__ gidx, int NG,
    ushort_t* __restrict__ attn_out) {
  __shared__ ushort_t buf0[128 * 72];  // K local rows -> V local rows
  __shared__ ushort_t buf1[128 * 72];  // K global c0  -> V global c0
  __shared__ ushort_t buf2[96 * 72];   // K global c1  -> V global c1

  const int tid = threadIdx.x;
  const int lane = tid & 63;
  const int w = tid >> 6;
  const int h = blockIdx.y;
  const int q0 = blockIdx.x * 64;

  const long hoff = (long)h * L_SEQ * DH;
  const ushort_t* Qh = QKV + hoff;
  const ushort_t* Kh = QKV + (long)NH * L_SEQ * DH + hoff;
  const ushort_t* Vh = QKV + 2L * NH * L_SEQ * DH + hoff;

  const int rr = tid >> 3;        // 0..31 (row per iteration)
  const int c8 = (tid & 7) * 8;   // element offset within 64-wide row

  // ---- stage K: local window rows + 204 global rows (clamped) ----
#pragma unroll
  for (int it = 0; it < 4; ++it) {
    int r = rr + it * 32;
    int sr = q0 - 32 + r;
    sr = sr < 0 ? 0 : (sr > L_SEQ - 1 ? L_SEQ - 1 : sr);
    int4 v = *(const int4*)(Kh + (long)sr * DH + c8);
    *(int4*)(buf0 + r * 72 + c8) = v;
  }
#pragma unroll
  for (int it = 0; it < 4; ++it) {
    int r = rr + it * 32;
    int idx = r < NG ? r : NG - 1;
    int4 v = *(const int4*)(Kh + (long)gidx[idx] * DH + c8);
    *(int4*)(buf1 + r * 72 + c8) = v;
  }
#pragma unroll
  for (int it = 0; it < 3; ++it) {
    int r = rr + it * 32;
    int i = 128 + r;
    int idx = i < NG ? i : NG - 1;
    int4 v = *(const int4*)(Kh + (long)gidx[idx] * DH + c8);
    *(int4*)(buf2 + r * 72 + c8) = v;
  }
  __syncthreads();

  // ---- Q fragments (B operand): n = lane&15 = query, k = d contiguous-8 ----
  const int l15 = lane & 15, lg = lane >> 4;
  const int ql = q0 + w * 16 + l15;
  bf16x8 qf0 = *(const bf16x8*)(Qh + (long)ql * DH + lg * 8);
  bf16x8 qf1 = *(const bf16x8*)(Qh + (long)ql * DH + 32 + lg * 8);

  // ---- S^T = K * Q^T ----
  f32x4 sl[8], sg[14];
#pragma unroll
  for (int kt = 0; kt < 8; ++kt) {
    f32x4 c = {};
    bf16x8 k0 = *(const bf16x8*)(buf0 + (kt * 16 + l15) * 72 + lg * 8);
    bf16x8 k1 = *(const bf16x8*)(buf0 + (kt * 16 + l15) * 72 + 32 + lg * 8);
    c = MFMA16(k0, qf0, c);
    c = MFMA16(k1, qf1, c);
    sl[kt] = c;
  }
#pragma unroll
  for (int kt = 0; kt < 8; ++kt) {
    f32x4 c = {};
    bf16x8 k0 = *(const bf16x8*)(buf1 + (kt * 16 + l15) * 72 + lg * 8);
    bf16x8 k1 = *(const bf16x8*)(buf1 + (kt * 16 + l15) * 72 + 32 + lg * 8);
    c = MFMA16(k0, qf0, c);
    c = MFMA16(k1, qf1, c);
    sg[kt] = c;
  }
#pragma unroll
  for (int kt = 0; kt < 6; ++kt) {
    f32x4 c = {};
    bf16x8 k0 = *(const bf16x8*)(buf2 + (kt * 16 + l15) * 72 + lg * 8);
    bf16x8 k1 = *(const bf16x8*)(buf2 + (kt * 16 + l15) * 72 + 32 + lg * 8);
    c = MFMA16(k0, qf0, c);
    c = MFMA16(k1, qf1, c);
    sg[8 + kt] = c;
  }
  __syncthreads();  // K buffers dead

  // ---- issue V global loads early (latency hides under softmax) ----
  int4 vst[11];
#pragma unroll
  for (int it = 0; it < 4; ++it) {
    int r = rr + it * 32;
    int sr = q0 - 32 + r;
    sr = sr < 0 ? 0 : (sr > L_SEQ - 1 ? L_SEQ - 1 : sr);
    vst[it] = *(const int4*)(Vh + (long)sr * DH + c8);
  }
#pragma unroll
  for (int it = 0; it < 4; ++it) {
    int r = rr + it * 32;
    int idx = r < NG ? r : NG - 1;
    vst[4 + it] = *(const int4*)(Vh + (long)gidx[idx] * DH + c8);
  }
#pragma unroll
  for (int it = 0; it < 3; ++it) {
    int i = 128 + rr + it * 32;
    int idx = i < NG ? i : NG - 1;
    vst[8 + it] = *(const int4*)(Vh + (long)gidx[idx] * DH + c8);
  }

  // ---- local softmax (per query = per lane&15 column; reduce over xor 16,32) ----
  float mx = NEG_INF;
#pragma unroll
  for (int kt = 0; kt < 8; ++kt)
#pragma unroll
    for (int r4 = 0; r4 < 4; ++r4) {
      int key = q0 - 32 + kt * 16 + lg * 4 + r4;
      int d = key - ql;
      bool valid = (key >= 0) && (key < L_SEQ) && (d <= 32) && (d >= -32);
      float v = valid ? sl[kt][r4] : NEG_INF;
      sl[kt][r4] = v;
      mx = fmaxf(mx, v);
    }
  mx = fmaxf(mx, __shfl_xor(mx, 16, 64));
  mx = fmaxf(mx, __shfl_xor(mx, 32, 64));
  float den = 0.f;
#pragma unroll
  for (int kt = 0; kt < 8; ++kt)
#pragma unroll
    for (int r4 = 0; r4 < 4; ++r4) {
      float e = __expf(sl[kt][r4] - mx);
      sl[kt][r4] = e;
      den += e;
    }
  den += __shfl_xor(den, 16, 64);
  den += __shfl_xor(den, 32, 64);
  const float psl = 0.7f / den;

  // ---- global softmax ----
  float mg = NEG_INF;
#pragma unroll
  for (int t = 0; t < 14; ++t)
#pragma unroll
    for (int r4 = 0; r4 < 4; ++r4) {
      int i = t * 16 + lg * 4 + r4;
      float v = (i < NG) ? sg[t][r4] : NEG_INF;
      sg[t][r4] = v;
      mg = fmaxf(mg, v);
    }
  mg = fmaxf(mg, __shfl_xor(mg, 16, 64));
  mg = fmaxf(mg, __shfl_xor(mg, 32, 64));
  float deng = 0.f;
#pragma unroll
  for (int t = 0; t < 14; ++t)
#pragma unroll
    for (int r4 = 0; r4 < 4; ++r4) {
      float e = __expf(sg[t][r4] - mg);
      sg[t][r4] = e;
      deng += e;
    }
  deng += __shfl_xor(deng, 16, 64);
  deng += __shfl_xor(deng, 32, 64);
  const float psg = 0.3f / deng;

  // ---- pack P to bf16 A-fragments (in-lane; half-split k-map) ----
  bf16x8 pl[4], pg[7];
#pragma unroll
  for (int s = 0; s < 4; ++s)
#pragma unroll
    for (int j = 0; j < 4; ++j) {
      pl[s][j]     = (short)f2b(sl[2 * s][j] * psl);
      pl[s][j + 4] = (short)f2b(sl[2 * s + 1][j] * psl);
    }
#pragma unroll
  for (int s = 0; s < 7; ++s)
#pragma unroll
    for (int j = 0; j < 4; ++j) {
      pg[s][j]     = (short)f2b(sg[2 * s][j] * psg);
      pg[s][j + 4] = (short)f2b(sg[2 * s + 1][j] * psg);
    }

  // ---- write V into LDS, then PV ----
#pragma unroll
  for (int it = 0; it < 4; ++it)
    *(int4*)(buf0 + (rr + it * 32) * 72 + c8) = vst[it];
#pragma unroll
  for (int it = 0; it < 4; ++it)
    *(int4*)(buf1 + (rr + it * 32) * 72 + c8) = vst[4 + it];
#pragma unroll
  for (int it = 0; it < 3; ++it)
    *(int4*)(buf2 + (rr + it * 32) * 72 + c8) = vst[8 + it];
  __syncthreads();

  f32x4 o4[4];
#pragma unroll
  for (int dt = 0; dt < 4; ++dt) {
    f32x4 c = {};
    const int dc = dt * 16 + l15;
#pragma unroll
    for (int s = 0; s < 4; ++s) {  // local, keys s*32..s*32+31
      bf16x8 vf;
#pragma unroll
      for (int j = 0; j < 8; ++j) {
        int key = s * 32 + lg * 4 + (j & 3) + 16 * (j >> 2);
        vf[j] = (short)buf0[key * 72 + dc];
      }
      c = MFMA16(pl[s], vf, c);
    }
#pragma unroll
    for (int s = 0; s < 4; ++s) {  // global c0
      bf16x8 vf;
#pragma unroll
      for (int j = 0; j < 8; ++j) {
        int key = s * 32 + lg * 4 + (j & 3) + 16 * (j >> 2);
        vf[j] = (short)buf1[key * 72 + dc];
      }
      c = MFMA16(pg[s], vf, c);
    }
#pragma unroll
    for (int s = 0; s < 3; ++s) {  // global c1 (keys 128+)
      bf16x8 vf;
#pragma unroll
      for (int j = 0; j < 8; ++j) {
        int key = s * 32 + lg * 4 + (j & 3) + 16 * (j >> 2);
        vf[j] = (short)buf2[key * 72 + dc];
      }
      c = MFMA16(pg[4 + s], vf, c);
    }
    o4[dt] = c;
  }

  // ---- store combined attention output, bf16 [L][D_MODEL] ----
#pragma unroll
  for (int dt = 0; dt < 4; ++dt)
#pragma unroll
    for (int r4 = 0; r4 < 4; ++r4) {
      int row = q0 + w * 16 + lg * 4 + r4;
      int dc = dt * 16 + l15;
      attn_out[(long)row * D_MODEL + h * DH + dc] = f2b(o4[dt][r4]);
    }
}

extern "C" void kernel_launch(void* const* d_in, const int* in_sizes, int n_in,
                              void* d_out, int out_size, void* d_ws, size_t ws_size,
                              hipStream_t stream) {
  const float* x  = (const float*)d_in[0];
  const float* Wq = (const float*)d_in[1];
  const float* bq = (const float*)d_in[2];
  const float* Wk = (const float*)d_in[3];
  const float* bk = (const float*)d_in[4];
  const float* Wv = (const float*)d_in[5];
  const float* bv = (const float*)d_in[6];
  const float* Wo = (const float*)d_in[7];
  const float* bo = (const float*)d_in[8];
  const int* gidx = (const int*)d_in[9];
  const int NG = in_sizes[9];

  ushort_t* ws = (ushort_t*)d_ws;
  ushort_t* xb   = ws;                  // x bf16:  2M elems
  ushort_t* wb   = ws + 2097152L;       // 4 weights bf16: 4 x 1M elems
  ushort_t* qkv  = ws + 6291456L;       // Q,K,V bf16 head-major: 3 x 2M
  ushort_t* attn = ws + 12582912L;      // attention out bf16 [L][D]: 2M

  cvt_kernel<<<6144, 256, 0, stream>>>(x, Wq, Wk, Wv, Wo, ws);
  gemm_bt<<<dim3(16, 8, 3), 256, 0, stream>>>(xb, wb, bq, bk, bv, qkv, 0);
  attn_kernel<<<dim3(32, 16), 256, 0, stream>>>(qkv, gidx, NG, attn);
  gemm_bt<<<dim3(16, 8, 1), 256, 0, stream>>>(attn, wb + 3145728L, bo, bo, bo,
                                              d_out, 1);
}

// Round 2
// 76.278 us; speedup vs baseline: 1.0096x; 1.0096x over previous
//
#include <hip/hip_runtime.h>
#include <hip/hip_bf16.h>
#include <stdint.h>

#define L_SEQ 2048
#define D_MODEL 1024
#define NH 16
#define DH 64
#define NEG_INF -1e9f
#define BM 128
#define BN 128
#define BK 32

typedef short bf16x8 __attribute__((ext_vector_type(8)));
typedef float f32x4 __attribute__((ext_vector_type(4)));
typedef unsigned short ushort_t;
typedef const __attribute__((address_space(1))) void* gas_t;
typedef __attribute__((address_space(3))) void* las_t;

#define MFMA16(a, b, c) __builtin_amdgcn_mfma_f32_16x16x32_bf16((a), (b), (c), 0, 0, 0)

__device__ __forceinline__ ushort_t f2b(float f) {
  union { float f; unsigned u; } v; v.f = f;
  unsigned r = v.u + 0x7fffu + ((v.u >> 16) & 1u);
  return (ushort_t)(r >> 16);
}

// ---------------- f32 -> bf16 conversion of x + 4 weights ----------------
__global__ __launch_bounds__(256) void cvt_kernel(
    const float* __restrict__ x, const float* __restrict__ wq,
    const float* __restrict__ wk, const float* __restrict__ wv,
    const float* __restrict__ wo, ushort_t* __restrict__ out) {
  long e = ((long)blockIdx.x * 256 + threadIdx.x) * 4;
  const float* src; long off;
  if (e < 2097152L)      { src = x;  off = e; }
  else if (e < 3145728L) { src = wq; off = e - 2097152L; }
  else if (e < 4194304L) { src = wk; off = e - 3145728L; }
  else if (e < 5242880L) { src = wv; off = e - 4194304L; }
  else                   { src = wo; off = e - 5242880L; }
  float4 v = *(const float4*)(src + off);
  ushort4 o;
  o.x = f2b(v.x); o.y = f2b(v.y); o.z = f2b(v.z); o.w = f2b(v.w);
  *(ushort4*)(out + e) = o;
}

// ---------------- bf16 NT GEMM, 8 waves per 128x128 tile ----------------
// A: [2048][1024] bf16 row-major, W: [1024][1024] bf16 row-major (N x K)
// mode 0: out bf16 head-major [NH][L][DH], scale 0.125 for z==0 (Q)
// mode 1: out f32 row-major [2048][1024]
// 512 threads = 8 waves as 2M x 4N; per-wave output 64x32 (acc[4][2]).
__global__ __launch_bounds__(512, 4) void gemm_bt(
    const ushort_t* __restrict__ A, const ushort_t* __restrict__ Wbase,
    const float* __restrict__ b0, const float* __restrict__ b1,
    const float* __restrict__ b2, void* __restrict__ outbase, int mode) {
  const int z = blockIdx.z;
  const ushort_t* W = Wbase + (long)z * (D_MODEL * D_MODEL);
  const float* bias = (z == 0) ? b0 : ((z == 1) ? b1 : b2);
  const float scale = (mode == 0 && z == 0) ? 0.125f : 1.0f;

  __shared__ ushort_t As[BM * BK];
  __shared__ ushort_t Bs[BN * BK];
  const int tid = threadIdx.x;
  const int lane = tid & 63;
  const int wid = tid >> 6;
  const int wm = wid >> 2, wn = wid & 3;   // 2M x 4N wave grid
  const int m0 = blockIdx.x * BM, n0 = blockIdx.y * BN;
  const int K = D_MODEL;
  const int l15 = lane & 15, lg8 = (lane >> 4) * 8;

  // staging: 512 thr x 16B = 8KB = one full tile each for A and B
  const int soff = tid * 16;           // byte offset into 8KB tile
  const int srow = soff >> 6;          // 64B per row (32 bf16)
  const int scol = (soff & 63) >> 1;   // element within row

  f32x4 acc[4][2] = {};

  for (int kt = 0; kt < K; kt += BK) {
    __builtin_amdgcn_global_load_lds(
        (gas_t)(const void*)(A + (long)(m0 + srow) * K + kt + scol),
        (las_t)(void*)((char*)As + soff), 16, 0, 0);
    __builtin_amdgcn_global_load_lds(
        (gas_t)(const void*)(W + (long)(n0 + srow) * K + kt + scol),
        (las_t)(void*)((char*)Bs + soff), 16, 0, 0);
    __syncthreads();
    bf16x8 af[4], bf[2];
#pragma unroll
    for (int t = 0; t < 4; ++t)
      af[t] = *(const bf16x8*)(As + (wm * 64 + t * 16 + l15) * BK + lg8);
#pragma unroll
    for (int t = 0; t < 2; ++t)
      bf[t] = *(const bf16x8*)(Bs + (wn * 32 + t * 16 + l15) * BK + lg8);
#pragma unroll
    for (int mt = 0; mt < 4; ++mt)
#pragma unroll
      for (int nt = 0; nt < 2; ++nt)
        acc[mt][nt] = MFMA16(af[mt], bf[nt], acc[mt][nt]);
    __syncthreads();
  }

  const int lg4 = (lane >> 4) * 4;
  if (mode == 0) {
    ushort_t* o = (ushort_t*)outbase + (long)z * ((long)NH * L_SEQ * DH);
#pragma unroll
    for (int mt = 0; mt < 4; ++mt)
#pragma unroll
      for (int nt = 0; nt < 2; ++nt)
#pragma unroll
        for (int r = 0; r < 4; ++r) {
          int row = m0 + wm * 64 + mt * 16 + lg4 + r;
          int col = n0 + wn * 32 + nt * 16 + l15;
          float v = (acc[mt][nt][r] + bias[col]) * scale;
          o[((long)(col >> 6) * L_SEQ + row) * DH + (col & 63)] = f2b(v);
        }
  } else {
    float* o = (float*)outbase;
#pragma unroll
    for (int mt = 0; mt < 4; ++mt)
#pragma unroll
      for (int nt = 0; nt < 2; ++nt)
#pragma unroll
        for (int r = 0; r < 4; ++r) {
          int row = m0 + wm * 64 + mt * 16 + lg4 + r;
          int col = n0 + wn * 32 + nt * 16 + l15;
          o[(long)row * D_MODEL + col] = acc[mt][nt][r] + bias[col];
        }
  }
}

// ---------------- fused local+global sparse attention ----------------
// Grid: (32 q-blocks, 16 heads), 256 threads (4 waves x 16 queries).
// Swapped QK^T (mfma(K,Q)): S^T tiles have col=lane&15=query, rows=keys.
__global__ __launch_bounds__(256) void attn_kernel(
    const ushort_t* __restrict__ QKV, const int* __restrict__ gidx, int NG,
    ushort_t* __restrict__ attn_out) {
  __shared__ ushort_t buf0[128 * 72];  // K local rows -> V local rows
  __shared__ ushort_t buf1[128 * 72];  // K global c0  -> V global c0
  __shared__ ushort_t buf2[96 * 72];   // K global c1  -> V global c1

  const int tid = threadIdx.x;
  const int lane = tid & 63;
  const int w = tid >> 6;
  const int h = blockIdx.y;
  const int q0 = blockIdx.x * 64;

  const long hoff = (long)h * L_SEQ * DH;
  const ushort_t* Qh = QKV + hoff;
  const ushort_t* Kh = QKV + (long)NH * L_SEQ * DH + hoff;
  const ushort_t* Vh = QKV + 2L * NH * L_SEQ * DH + hoff;

  const int rr = tid >> 3;        // 0..31 (row per iteration)
  const int c8 = (tid & 7) * 8;   // element offset within 64-wide row

  // ---- stage K: local window rows + 204 global rows (clamped) ----
#pragma unroll
  for (int it = 0; it < 4; ++it) {
    int r = rr + it * 32;
    int sr = q0 - 32 + r;
    sr = sr < 0 ? 0 : (sr > L_SEQ - 1 ? L_SEQ - 1 : sr);
    int4 v = *(const int4*)(Kh + (long)sr * DH + c8);
    *(int4*)(buf0 + r * 72 + c8) = v;
  }
#pragma unroll
  for (int it = 0; it < 4; ++it) {
    int r = rr + it * 32;
    int idx = r < NG ? r : NG - 1;
    int4 v = *(const int4*)(Kh + (long)gidx[idx] * DH + c8);
    *(int4*)(buf1 + r * 72 + c8) = v;
  }
#pragma unroll
  for (int it = 0; it < 3; ++it) {
    int r = rr + it * 32;
    int i = 128 + r;
    int idx = i < NG ? i : NG - 1;
    int4 v = *(const int4*)(Kh + (long)gidx[idx] * DH + c8);
    *(int4*)(buf2 + r * 72 + c8) = v;
  }
  __syncthreads();

  // ---- Q fragments (B operand): n = lane&15 = query, k = d contiguous-8 ----
  const int l15 = lane & 15, lg = lane >> 4;
  const int ql = q0 + w * 16 + l15;
  bf16x8 qf0 = *(const bf16x8*)(Qh + (long)ql * DH + lg * 8);
  bf16x8 qf1 = *(const bf16x8*)(Qh + (long)ql * DH + 32 + lg * 8);

  // ---- S^T = K * Q^T ----
  f32x4 sl[8], sg[14];
#pragma unroll
  for (int kt = 0; kt < 8; ++kt) {
    f32x4 c = {};
    bf16x8 k0 = *(const bf16x8*)(buf0 + (kt * 16 + l15) * 72 + lg * 8);
    bf16x8 k1 = *(const bf16x8*)(buf0 + (kt * 16 + l15) * 72 + 32 + lg * 8);
    c = MFMA16(k0, qf0, c);
    c = MFMA16(k1, qf1, c);
    sl[kt] = c;
  }
#pragma unroll
  for (int kt = 0; kt < 8; ++kt) {
    f32x4 c = {};
    bf16x8 k0 = *(const bf16x8*)(buf1 + (kt * 16 + l15) * 72 + lg * 8);
    bf16x8 k1 = *(const bf16x8*)(buf1 + (kt * 16 + l15) * 72 + 32 + lg * 8);
    c = MFMA16(k0, qf0, c);
    c = MFMA16(k1, qf1, c);
    sg[kt] = c;
  }
#pragma unroll
  for (int kt = 0; kt < 6; ++kt) {
    f32x4 c = {};
    bf16x8 k0 = *(const bf16x8*)(buf2 + (kt * 16 + l15) * 72 + lg * 8);
    bf16x8 k1 = *(const bf16x8*)(buf2 + (kt * 16 + l15) * 72 + 32 + lg * 8);
    c = MFMA16(k0, qf0, c);
    c = MFMA16(k1, qf1, c);
    sg[8 + kt] = c;
  }
  __syncthreads();  // K buffers dead

  // ---- issue V global loads early (latency hides under softmax) ----
  int4 vst[11];
#pragma unroll
  for (int it = 0; it < 4; ++it) {
    int r = rr + it * 32;
    int sr = q0 - 32 + r;
    sr = sr < 0 ? 0 : (sr > L_SEQ - 1 ? L_SEQ - 1 : sr);
    vst[it] = *(const int4*)(Vh + (long)sr * DH + c8);
  }
#pragma unroll
  for (int it = 0; it < 4; ++it) {
    int r = rr + it * 32;
    int idx = r < NG ? r : NG - 1;
    vst[4 + it] = *(const int4*)(Vh + (long)gidx[idx] * DH + c8);
  }
#pragma unroll
  for (int it = 0; it < 3; ++it) {
    int i = 128 + rr + it * 32;
    int idx = i < NG ? i : NG - 1;
    vst[8 + it] = *(const int4*)(Vh + (long)gidx[idx] * DH + c8);
  }

  // ---- local softmax (per query = per lane&15 column; reduce over xor 16,32) ----
  float mx = NEG_INF;
#pragma unroll
  for (int kt = 0; kt < 8; ++kt)
#pragma unroll
    for (int r4 = 0; r4 < 4; ++r4) {
      int key = q0 - 32 + kt * 16 + lg * 4 + r4;
      int d = key - ql;
      bool valid = (key >= 0) && (key < L_SEQ) && (d <= 32) && (d >= -32);
      float v = valid ? sl[kt][r4] : NEG_INF;
      sl[kt][r4] = v;
      mx = fmaxf(mx, v);
    }
  mx = fmaxf(mx, __shfl_xor(mx, 16, 64));
  mx = fmaxf(mx, __shfl_xor(mx, 32, 64));
  float den = 0.f;
#pragma unroll
  for (int kt = 0; kt < 8; ++kt)
#pragma unroll
    for (int r4 = 0; r4 < 4; ++r4) {
      float e = __expf(sl[kt][r4] - mx);
      sl[kt][r4] = e;
      den += e;
    }
  den += __shfl_xor(den, 16, 64);
  den += __shfl_xor(den, 32, 64);
  const float psl = 0.7f / den;

  // ---- global softmax ----
  float mg = NEG_INF;
#pragma unroll
  for (int t = 0; t < 14; ++t)
#pragma unroll
    for (int r4 = 0; r4 < 4; ++r4) {
      int i = t * 16 + lg * 4 + r4;
      float v = (i < NG) ? sg[t][r4] : NEG_INF;
      sg[t][r4] = v;
      mg = fmaxf(mg, v);
    }
  mg = fmaxf(mg, __shfl_xor(mg, 16, 64));
  mg = fmaxf(mg, __shfl_xor(mg, 32, 64));
  float deng = 0.f;
#pragma unroll
  for (int t = 0; t < 14; ++t)
#pragma unroll
    for (int r4 = 0; r4 < 4; ++r4) {
      float e = __expf(sg[t][r4] - mg);
      sg[t][r4] = e;
      deng += e;
    }
  deng += __shfl_xor(deng, 16, 64);
  deng += __shfl_xor(deng, 32, 64);
  const float psg = 0.3f / deng;

  // ---- pack P to bf16 A-fragments (in-lane; half-split k-map) ----
  bf16x8 pl[4], pg[7];
#pragma unroll
  for (int s = 0; s < 4; ++s)
#pragma unroll
    for (int j = 0; j < 4; ++j) {
      pl[s][j]     = (short)f2b(sl[2 * s][j] * psl);
      pl[s][j + 4] = (short)f2b(sl[2 * s + 1][j] * psl);
    }
#pragma unroll
  for (int s = 0; s < 7; ++s)
#pragma unroll
    for (int j = 0; j < 4; ++j) {
      pg[s][j]     = (short)f2b(sg[2 * s][j] * psg);
      pg[s][j + 4] = (short)f2b(sg[2 * s + 1][j] * psg);
    }

  // ---- write V into LDS, then PV ----
#pragma unroll
  for (int it = 0; it < 4; ++it)
    *(int4*)(buf0 + (rr + it * 32) * 72 + c8) = vst[it];
#pragma unroll
  for (int it = 0; it < 4; ++it)
    *(int4*)(buf1 + (rr + it * 32) * 72 + c8) = vst[4 + it];
#pragma unroll
  for (int it = 0; it < 3; ++it)
    *(int4*)(buf2 + (rr + it * 32) * 72 + c8) = vst[8 + it];
  __syncthreads();

  f32x4 o4[4];
#pragma unroll
  for (int dt = 0; dt < 4; ++dt) {
    f32x4 c = {};
    const int dc = dt * 16 + l15;
#pragma unroll
    for (int s = 0; s < 4; ++s) {  // local, keys s*32..s*32+31
      bf16x8 vf;
#pragma unroll
      for (int j = 0; j < 8; ++j) {
        int key = s * 32 + lg * 4 + (j & 3) + 16 * (j >> 2);
        vf[j] = (short)buf0[key * 72 + dc];
      }
      c = MFMA16(pl[s], vf, c);
    }
#pragma unroll
    for (int s = 0; s < 4; ++s) {  // global c0
      bf16x8 vf;
#pragma unroll
      for (int j = 0; j < 8; ++j) {
        int key = s * 32 + lg * 4 + (j & 3) + 16 * (j >> 2);
        vf[j] = (short)buf1[key * 72 + dc];
      }
      c = MFMA16(pg[s], vf, c);
    }
#pragma unroll
    for (int s = 0; s < 3; ++s) {  // global c1 (keys 128+)
      bf16x8 vf;
#pragma unroll
      for (int j = 0; j < 8; ++j) {
        int key = s * 32 + lg * 4 + (j & 3) + 16 * (j >> 2);
        vf[j] = (short)buf2[key * 72 + dc];
      }
      c = MFMA16(pg[4 + s], vf, c);
    }
    o4[dt] = c;
  }

  // ---- store combined attention output, bf16 [L][D_MODEL] ----
#pragma unroll
  for (int dt = 0; dt < 4; ++dt)
#pragma unroll
    for (int r4 = 0; r4 < 4; ++r4) {
      int row = q0 + w * 16 + lg * 4 + r4;
      int dc = dt * 16 + l15;
      attn_out[(long)row * D_MODEL + h * DH + dc] = f2b(o4[dt][r4]);
    }
}

extern "C" void kernel_launch(void* const* d_in, const int* in_sizes, int n_in,
                              void* d_out, int out_size, void* d_ws, size_t ws_size,
                              hipStream_t stream) {
  const float* x  = (const float*)d_in[0];
  const float* Wq = (const float*)d_in[1];
  const float* bq = (const float*)d_in[2];
  const float* Wk = (const float*)d_in[3];
  const float* bk = (const float*)d_in[4];
  const float* Wv = (const float*)d_in[5];
  const float* bv = (const float*)d_in[6];
  const float* Wo = (const float*)d_in[7];
  const float* bo = (const float*)d_in[8];
  const int* gidx = (const int*)d_in[9];
  const int NG = in_sizes[9];

  ushort_t* ws = (ushort_t*)d_ws;
  ushort_t* xb   = ws;                  // x bf16:  2M elems
  ushort_t* wb   = ws + 2097152L;       // 4 weights bf16: 4 x 1M elems
  ushort_t* qkv  = ws + 6291456L;       // Q,K,V bf16 head-major: 3 x 2M
  ushort_t* attn = ws + 12582912L;      // attention out bf16 [L][D]: 2M

  cvt_kernel<<<6144, 256, 0, stream>>>(x, Wq, Wk, Wv, Wo, ws);
  gemm_bt<<<dim3(16, 8, 3), 512, 0, stream>>>(xb, wb, bq, bk, bv, qkv, 0);
  attn_kernel<<<dim3(32, 16), 256, 0, stream>>>(qkv, gidx, NG, attn);
  gemm_bt<<<dim3(16, 8, 1), 512, 0, stream>>>(attn, wb + 3145728L, bo, bo, bo,
                                              d_out, 1);
}

// Round 3
// 65.327 us; speedup vs baseline: 1.1789x; 1.1676x over previous
//
#include <hip/hip_runtime.h>
#include <hip/hip_bf16.h>
#include <stdint.h>

#define L_SEQ 2048
#define D_MODEL 1024
#define NH 16
#define DH 64
#define NEG_INF -1e9f
#define BM 128
#define BN 128
#define BK 32

typedef short bf16x8 __attribute__((ext_vector_type(8)));
typedef float f32x4 __attribute__((ext_vector_type(4)));
typedef unsigned short ushort_t;
typedef const __attribute__((address_space(1))) void* gas_t;
typedef __attribute__((address_space(3))) void* las_t;

#define MFMA16(a, b, c) __builtin_amdgcn_mfma_f32_16x16x32_bf16((a), (b), (c), 0, 0, 0)

__device__ __forceinline__ ushort_t f2b(float f) {
  union { float f; unsigned u; } v; v.f = f;
  unsigned r = v.u + 0x7fffu + ((v.u >> 16) & 1u);
  return (ushort_t)(r >> 16);
}

// ---------------- f32 -> bf16 conversion of x + 4 weights ----------------
__global__ __launch_bounds__(256) void cvt_kernel(
    const float* __restrict__ x, const float* __restrict__ wq,
    const float* __restrict__ wk, const float* __restrict__ wv,
    const float* __restrict__ wo, ushort_t* __restrict__ out) {
  long e = ((long)blockIdx.x * 256 + threadIdx.x) * 4;
  const float* src; long off;
  if (e < 2097152L)      { src = x;  off = e; }
  else if (e < 3145728L) { src = wq; off = e - 2097152L; }
  else if (e < 4194304L) { src = wk; off = e - 3145728L; }
  else if (e < 5242880L) { src = wv; off = e - 4194304L; }
  else                   { src = wo; off = e - 5242880L; }
  float4 v = *(const float4*)(src + off);
  ushort4 o;
  o.x = f2b(v.x); o.y = f2b(v.y); o.z = f2b(v.z); o.w = f2b(v.w);
  *(ushort4*)(out + e) = o;
}

// ---------------- bf16 NT GEMM, ring-4 counted-vmcnt pipeline ----------------
// A: [2048][1024] bf16 row-major, W: [1024][1024] bf16 row-major (N x K)
// mode 0: out bf16 head-major [NH][L][DH], scale 0.125 for z==0 (Q)
// mode 1: out f32 row-major [2048][1024]
// 512 threads = 8 waves (2M x 4N); per-wave output 64x32 (acc[4][2]).
// K-loop: prefetch distance 2 into a 4-buffer LDS ring; raw s_barrier +
// s_waitcnt vmcnt(N) (never 0 until tail) so loads stay in flight across
// the barrier (T3+T4).
__global__ __launch_bounds__(512, 4) void gemm_bt(
    const ushort_t* __restrict__ A, const ushort_t* __restrict__ Wbase,
    const float* __restrict__ b0, const float* __restrict__ b1,
    const float* __restrict__ b2, void* __restrict__ outbase, int mode) {
  const int z = blockIdx.z;
  const ushort_t* W = Wbase + (long)z * (D_MODEL * D_MODEL);
  const float* bias = (z == 0) ? b0 : ((z == 1) ? b1 : b2);
  const float scale = (mode == 0 && z == 0) ? 0.125f : 1.0f;

  __shared__ ushort_t As[4 * BM * BK];  // 4 ring buffers x 8KB
  __shared__ ushort_t Bs[4 * BN * BK];
  const int tid = threadIdx.x;
  const int lane = tid & 63;
  const int wid = tid >> 6;
  const int wm = wid >> 2, wn = wid & 3;   // 2M x 4N wave grid
  const int m0 = blockIdx.x * BM, n0 = blockIdx.y * BN;
  const int K = D_MODEL;
  const int l15 = lane & 15, lg8 = (lane >> 4) * 8;

  // staging: 512 thr x 16B = 8KB = one full 128x32 tile per matrix
  const int soff = tid * 16;           // byte offset into 8KB tile
  const int srow = soff >> 6;          // 64B per row (32 bf16)
  const int scol = (soff & 63) >> 1;   // element within row

  const ushort_t* Aptr = A + (long)(m0 + srow) * K + scol;
  const ushort_t* Wptr = W + (long)(n0 + srow) * K + scol;

  auto stage = [&](int buf, int step) {
    __builtin_amdgcn_global_load_lds(
        (gas_t)(const void*)(Aptr + step * BK),
        (las_t)(void*)((char*)As + buf * 8192 + soff), 16, 0, 0);
    __builtin_amdgcn_global_load_lds(
        (gas_t)(const void*)(Wptr + step * BK),
        (las_t)(void*)((char*)Bs + buf * 8192 + soff), 16, 0, 0);
  };

  f32x4 acc[4][2] = {};

  auto compute = [&](int buf) {
    const ushort_t* Ab = As + buf * (BM * BK);
    const ushort_t* Bb = Bs + buf * (BN * BK);
    bf16x8 af[4], bf[2];
#pragma unroll
    for (int t = 0; t < 4; ++t)
      af[t] = *(const bf16x8*)(Ab + (wm * 64 + t * 16 + l15) * BK + lg8);
#pragma unroll
    for (int t = 0; t < 2; ++t)
      bf[t] = *(const bf16x8*)(Bb + (wn * 32 + t * 16 + l15) * BK + lg8);
#pragma unroll
    for (int mt = 0; mt < 4; ++mt)
#pragma unroll
      for (int nt = 0; nt < 2; ++nt)
        acc[mt][nt] = MFMA16(af[mt], bf[nt], acc[mt][nt]);
  };

  const int NSTEP = K / BK;  // 32
  stage(0, 0);
  stage(1, 1);
  for (int s = 0; s < NSTEP - 2; ++s) {
    stage((s + 2) & 3, s + 2);
    asm volatile("s_waitcnt vmcnt(4)" ::: "memory");
    __builtin_amdgcn_s_barrier();
    __builtin_amdgcn_sched_barrier(0);
    compute(s & 3);
  }
  // s = NSTEP-2: only stages NSTEP-1 (2 loads) may be outstanding beyond it
  asm volatile("s_waitcnt vmcnt(2)" ::: "memory");
  __builtin_amdgcn_s_barrier();
  __builtin_amdgcn_sched_barrier(0);
  compute((NSTEP - 2) & 3);
  // s = NSTEP-1: drain everything
  asm volatile("s_waitcnt vmcnt(0)" ::: "memory");
  __builtin_amdgcn_s_barrier();
  __builtin_amdgcn_sched_barrier(0);
  compute((NSTEP - 1) & 3);

  const int lg4 = (lane >> 4) * 4;
  if (mode == 0) {
    ushort_t* o = (ushort_t*)outbase + (long)z * ((long)NH * L_SEQ * DH);
#pragma unroll
    for (int mt = 0; mt < 4; ++mt)
#pragma unroll
      for (int nt = 0; nt < 2; ++nt)
#pragma unroll
        for (int r = 0; r < 4; ++r) {
          int row = m0 + wm * 64 + mt * 16 + lg4 + r;
          int col = n0 + wn * 32 + nt * 16 + l15;
          float v = (acc[mt][nt][r] + bias[col]) * scale;
          o[((long)(col >> 6) * L_SEQ + row) * DH + (col & 63)] = f2b(v);
        }
  } else {
    float* o = (float*)outbase;
#pragma unroll
    for (int mt = 0; mt < 4; ++mt)
#pragma unroll
      for (int nt = 0; nt < 2; ++nt)
#pragma unroll
        for (int r = 0; r < 4; ++r) {
          int row = m0 + wm * 64 + mt * 16 + lg4 + r;
          int col = n0 + wn * 32 + nt * 16 + l15;
          o[(long)row * D_MODEL + col] = acc[mt][nt][r] + bias[col];
        }
  }
}

// ---------------- fused local+global sparse attention ----------------
// Grid: (32 q-blocks, 16 heads), 256 threads (4 waves x 16 queries).
// Swapped QK^T (mfma(K,Q)): S^T tiles have col=lane&15=query, rows=keys.
__global__ __launch_bounds__(256) void attn_kernel(
    const ushort_t* __restrict__ QKV, const int* __restrict__ gidx, int NG,
    ushort_t* __restrict__ attn_out) {
  __shared__ ushort_t buf0[128 * 72];  // K local rows -> V local rows
  __shared__ ushort_t buf1[128 * 72];  // K global c0  -> V global c0
  __shared__ ushort_t buf2[96 * 72];   // K global c1  -> V global c1

  const int tid = threadIdx.x;
  const int lane = tid & 63;
  const int w = tid >> 6;
  const int h = blockIdx.y;
  const int q0 = blockIdx.x * 64;

  const long hoff = (long)h * L_SEQ * DH;
  const ushort_t* Qh = QKV + hoff;
  const ushort_t* Kh = QKV + (long)NH * L_SEQ * DH + hoff;
  const ushort_t* Vh = QKV + 2L * NH * L_SEQ * DH + hoff;

  const int rr = tid >> 3;        // 0..31 (row per iteration)
  const int c8 = (tid & 7) * 8;   // element offset within 64-wide row

  // ---- stage K: local window rows + 204 global rows (clamped) ----
#pragma unroll
  for (int it = 0; it < 4; ++it) {
    int r = rr + it * 32;
    int sr = q0 - 32 + r;
    sr = sr < 0 ? 0 : (sr > L_SEQ - 1 ? L_SEQ - 1 : sr);
    int4 v = *(const int4*)(Kh + (long)sr * DH + c8);
    *(int4*)(buf0 + r * 72 + c8) = v;
  }
#pragma unroll
  for (int it = 0; it < 4; ++it) {
    int r = rr + it * 32;
    int idx = r < NG ? r : NG - 1;
    int4 v = *(const int4*)(Kh + (long)gidx[idx] * DH + c8);
    *(int4*)(buf1 + r * 72 + c8) = v;
  }
#pragma unroll
  for (int it = 0; it < 3; ++it) {
    int r = rr + it * 32;
    int i = 128 + r;
    int idx = i < NG ? i : NG - 1;
    int4 v = *(const int4*)(Kh + (long)gidx[idx] * DH + c8);
    *(int4*)(buf2 + r * 72 + c8) = v;
  }
  __syncthreads();

  // ---- Q fragments (B operand): n = lane&15 = query, k = d contiguous-8 ----
  const int l15 = lane & 15, lg = lane >> 4;
  const int ql = q0 + w * 16 + l15;
  bf16x8 qf0 = *(const bf16x8*)(Qh + (long)ql * DH + lg * 8);
  bf16x8 qf1 = *(const bf16x8*)(Qh + (long)ql * DH + 32 + lg * 8);

  // ---- S^T = K * Q^T ----
  f32x4 sl[8], sg[14];
#pragma unroll
  for (int kt = 0; kt < 8; ++kt) {
    f32x4 c = {};
    bf16x8 k0 = *(const bf16x8*)(buf0 + (kt * 16 + l15) * 72 + lg * 8);
    bf16x8 k1 = *(const bf16x8*)(buf0 + (kt * 16 + l15) * 72 + 32 + lg * 8);
    c = MFMA16(k0, qf0, c);
    c = MFMA16(k1, qf1, c);
    sl[kt] = c;
  }
#pragma unroll
  for (int kt = 0; kt < 8; ++kt) {
    f32x4 c = {};
    bf16x8 k0 = *(const bf16x8*)(buf1 + (kt * 16 + l15) * 72 + lg * 8);
    bf16x8 k1 = *(const bf16x8*)(buf1 + (kt * 16 + l15) * 72 + 32 + lg * 8);
    c = MFMA16(k0, qf0, c);
    c = MFMA16(k1, qf1, c);
    sg[kt] = c;
  }
#pragma unroll
  for (int kt = 0; kt < 6; ++kt) {
    f32x4 c = {};
    bf16x8 k0 = *(const bf16x8*)(buf2 + (kt * 16 + l15) * 72 + lg * 8);
    bf16x8 k1 = *(const bf16x8*)(buf2 + (kt * 16 + l15) * 72 + 32 + lg * 8);
    c = MFMA16(k0, qf0, c);
    c = MFMA16(k1, qf1, c);
    sg[8 + kt] = c;
  }
  __syncthreads();  // K buffers dead

  // ---- issue V global loads early (latency hides under softmax) ----
  int4 vst[11];
#pragma unroll
  for (int it = 0; it < 4; ++it) {
    int r = rr + it * 32;
    int sr = q0 - 32 + r;
    sr = sr < 0 ? 0 : (sr > L_SEQ - 1 ? L_SEQ - 1 : sr);
    vst[it] = *(const int4*)(Vh + (long)sr * DH + c8);
  }
#pragma unroll
  for (int it = 0; it < 4; ++it) {
    int r = rr + it * 32;
    int idx = r < NG ? r : NG - 1;
    vst[4 + it] = *(const int4*)(Vh + (long)gidx[idx] * DH + c8);
  }
#pragma unroll
  for (int it = 0; it < 3; ++it) {
    int i = 128 + rr + it * 32;
    int idx = i < NG ? i : NG - 1;
    vst[8 + it] = *(const int4*)(Vh + (long)gidx[idx] * DH + c8);
  }

  // ---- local softmax (per query = per lane&15 column; reduce over xor 16,32) ----
  float mx = NEG_INF;
#pragma unroll
  for (int kt = 0; kt < 8; ++kt)
#pragma unroll
    for (int r4 = 0; r4 < 4; ++r4) {
      int key = q0 - 32 + kt * 16 + lg * 4 + r4;
      int d = key - ql;
      bool valid = (key >= 0) && (key < L_SEQ) && (d <= 32) && (d >= -32);
      float v = valid ? sl[kt][r4] : NEG_INF;
      sl[kt][r4] = v;
      mx = fmaxf(mx, v);
    }
  mx = fmaxf(mx, __shfl_xor(mx, 16, 64));
  mx = fmaxf(mx, __shfl_xor(mx, 32, 64));
  float den = 0.f;
#pragma unroll
  for (int kt = 0; kt < 8; ++kt)
#pragma unroll
    for (int r4 = 0; r4 < 4; ++r4) {
      float e = __expf(sl[kt][r4] - mx);
      sl[kt][r4] = e;
      den += e;
    }
  den += __shfl_xor(den, 16, 64);
  den += __shfl_xor(den, 32, 64);
  const float psl = 0.7f / den;

  // ---- global softmax ----
  float mg = NEG_INF;
#pragma unroll
  for (int t = 0; t < 14; ++t)
#pragma unroll
    for (int r4 = 0; r4 < 4; ++r4) {
      int i = t * 16 + lg * 4 + r4;
      float v = (i < NG) ? sg[t][r4] : NEG_INF;
      sg[t][r4] = v;
      mg = fmaxf(mg, v);
    }
  mg = fmaxf(mg, __shfl_xor(mg, 16, 64));
  mg = fmaxf(mg, __shfl_xor(mg, 32, 64));
  float deng = 0.f;
#pragma unroll
  for (int t = 0; t < 14; ++t)
#pragma unroll
    for (int r4 = 0; r4 < 4; ++r4) {
      float e = __expf(sg[t][r4] - mg);
      sg[t][r4] = e;
      deng += e;
    }
  deng += __shfl_xor(deng, 16, 64);
  deng += __shfl_xor(deng, 32, 64);
  const float psg = 0.3f / deng;

  // ---- pack P to bf16 A-fragments (in-lane; half-split k-map) ----
  bf16x8 pl[4], pg[7];
#pragma unroll
  for (int s = 0; s < 4; ++s)
#pragma unroll
    for (int j = 0; j < 4; ++j) {
      pl[s][j]     = (short)f2b(sl[2 * s][j] * psl);
      pl[s][j + 4] = (short)f2b(sl[2 * s + 1][j] * psl);
    }
#pragma unroll
  for (int s = 0; s < 7; ++s)
#pragma unroll
    for (int j = 0; j < 4; ++j) {
      pg[s][j]     = (short)f2b(sg[2 * s][j] * psg);
      pg[s][j + 4] = (short)f2b(sg[2 * s + 1][j] * psg);
    }

  // ---- write V into LDS, then PV ----
#pragma unroll
  for (int it = 0; it < 4; ++it)
    *(int4*)(buf0 + (rr + it * 32) * 72 + c8) = vst[it];
#pragma unroll
  for (int it = 0; it < 4; ++it)
    *(int4*)(buf1 + (rr + it * 32) * 72 + c8) = vst[4 + it];
#pragma unroll
  for (int it = 0; it < 3; ++it)
    *(int4*)(buf2 + (rr + it * 32) * 72 + c8) = vst[8 + it];
  __syncthreads();

  f32x4 o4[4];
#pragma unroll
  for (int dt = 0; dt < 4; ++dt) {
    f32x4 c = {};
    const int dc = dt * 16 + l15;
#pragma unroll
    for (int s = 0; s < 4; ++s) {  // local, keys s*32..s*32+31
      bf16x8 vf;
#pragma unroll
      for (int j = 0; j < 8; ++j) {
        int key = s * 32 + lg * 4 + (j & 3) + 16 * (j >> 2);
        vf[j] = (short)buf0[key * 72 + dc];
      }
      c = MFMA16(pl[s], vf, c);
    }
#pragma unroll
    for (int s = 0; s < 4; ++s) {  // global c0
      bf16x8 vf;
#pragma unroll
      for (int j = 0; j < 8; ++j) {
        int key = s * 32 + lg * 4 + (j & 3) + 16 * (j >> 2);
        vf[j] = (short)buf1[key * 72 + dc];
      }
      c = MFMA16(pg[s], vf, c);
    }
#pragma unroll
    for (int s = 0; s < 3; ++s) {  // global c1 (keys 128+)
      bf16x8 vf;
#pragma unroll
      for (int j = 0; j < 8; ++j) {
        int key = s * 32 + lg * 4 + (j & 3) + 16 * (j >> 2);
        vf[j] = (short)buf2[key * 72 + dc];
      }
      c = MFMA16(pg[4 + s], vf, c);
    }
    o4[dt] = c;
  }

  // ---- store combined attention output, bf16 [L][D_MODEL] ----
#pragma unroll
  for (int dt = 0; dt < 4; ++dt)
#pragma unroll
    for (int r4 = 0; r4 < 4; ++r4) {
      int row = q0 + w * 16 + lg * 4 + r4;
      int dc = dt * 16 + l15;
      attn_out[(long)row * D_MODEL + h * DH + dc] = f2b(o4[dt][r4]);
    }
}

extern "C" void kernel_launch(void* const* d_in, const int* in_sizes, int n_in,
                              void* d_out, int out_size, void* d_ws, size_t ws_size,
                              hipStream_t stream) {
  const float* x  = (const float*)d_in[0];
  const float* Wq = (const float*)d_in[1];
  const float* bq = (const float*)d_in[2];
  const float* Wk = (const float*)d_in[3];
  const float* bk = (const float*)d_in[4];
  const float* Wv = (const float*)d_in[5];
  const float* bv = (const float*)d_in[6];
  const float* Wo = (const float*)d_in[7];
  const float* bo = (const float*)d_in[8];
  const int* gidx = (const int*)d_in[9];
  const int NG = in_sizes[9];

  ushort_t* ws = (ushort_t*)d_ws;
  ushort_t* xb   = ws;                  // x bf16:  2M elems
  ushort_t* wb   = ws + 2097152L;       // 4 weights bf16: 4 x 1M elems
  ushort_t* qkv  = ws + 6291456L;       // Q,K,V bf16 head-major: 3 x 2M
  ushort_t* attn = ws + 12582912L;      // attention out bf16 [L][D]: 2M

  cvt_kernel<<<6144, 256, 0, stream>>>(x, Wq, Wk, Wv, Wo, ws);
  gemm_bt<<<dim3(16, 8, 3), 512, 0, stream>>>(xb, wb, bq, bk, bv, qkv, 0);
  attn_kernel<<<dim3(32, 16), 256, 0, stream>>>(qkv, gidx, NG, attn);
  gemm_bt<<<dim3(16, 8, 1), 512, 0, stream>>>(attn, wb + 3145728L, bo, bo, bo,
                                              d_out, 1);
}